// Round 3
// baseline (296.294 us; speedup 1.0000x reference)
//
#include <hip/hip_runtime.h>

#define EMB 2048
#define UDIM 256
#define KTOT 2304
#define NE 64
#define TOPK 8
#define LP 65                 // epilogue slab row stride
#define SSH 6144              // shorts per k-step in wb (12288 B)
#define STEPB 12288           // bytes per k-step
#define CH 4                  // k-steps per staged chunk (128 k)
#define CHB (CH * STEPB)      // 49152 B per chunk
#define NCHUNK 18             // 72 k-steps total

typedef __attribute__((ext_vector_type(8))) short short8;
typedef __attribute__((ext_vector_type(4))) float f32x4;
typedef __attribute__((ext_vector_type(4))) unsigned int u32x4;

__device__ __forceinline__ unsigned short bf16h(float x) {
  unsigned uu = __builtin_bit_cast(unsigned, x);
  return (unsigned short)((uu + 0x7FFFu + ((uu >> 16) & 1u)) >> 16);
}
__device__ __forceinline__ float bf2f(unsigned short s) {
  return __builtin_bit_cast(float, ((unsigned)s) << 16);
}

// packed RNE f32x2 -> bf16x2
__device__ __forceinline__ unsigned cvtpk(float a, float b) {
  unsigned r;
  asm("v_cvt_pk_bf16_f32 %0, %1, %2" : "=v"(r) : "v"(a), "v"(b));
  return r;
}

// ---- prep: W fp32 [2304][64] -> triple-split bf16 in MFMA-FRAGMENT order ----
// wb[kstep][plane][nt][lane][j]:  lane = (kk>>3)*16 + (n&15), j = kk&7
__global__ __launch_bounds__(256)
void prep_w(const float* __restrict__ W, unsigned short* __restrict__ wb) {
  const int flat = blockIdx.x * 256 + threadIdx.x;  // 0..147455
  const int k = flat >> 6;
  const int n = flat & 63;
  const float w = W[flat];
  const unsigned short h0 = bf16h(w);
  const float r1 = w - bf2f(h0);   // exact in fp32
  const unsigned short h1 = bf16h(r1);
  const float r2 = r1 - bf2f(h1);  // exact in fp32
  const unsigned short h2 = bf16h(r2);

  const int s = k >> 5;
  const int kk = k & 31;
  const int lane = (kk >> 3) * 16 + (n & 15);
  const int j = kk & 7;
  const int nt = n >> 4;
  const size_t base = (size_t)s * SSH + ((size_t)nt * 64 + lane) * 8 + j;
  wb[base] = h0;
  wb[base + 2048] = h1;
  wb[base + 4096] = h2;
}

// ---- main: LDS-shared B, full-K per wave, no inter-wave reduce ----
// 4 waves/block, 1 token-tile (16 tok) per wave, 64 tok/block, 256 blocks.
// B staged to LDS once per block (226 MB total vs 906 MB direct-L2).
__global__ __launch_bounds__(256, 1)
void gate_mfma(const float* __restrict__ h, const float* __restrict__ u,
               const unsigned short* __restrict__ wb,
               const float* __restrict__ b, float* __restrict__ out) {
  __shared__ __align__(1024) char lds[2 * CHB];  // 96 KB double-buffer

  const int tid = threadIdx.x;
  const int lane = tid & 63;
  const int wid = __builtin_amdgcn_readfirstlane(tid >> 6);  // 0..3
  const int mm = lane & 15;        // A: token-in-tile | B: expert-in-tile
  const int q8 = (lane >> 4) * 8;  // k-subgroup within frag
  const int tok0 = blockIdx.x * 64;
  const int token = tok0 + wid * 16 + mm;

  const float* hrow = h + (size_t)token * EMB + q8;
  const float* urow = u + (size_t)token * UDIM + q8;

  // wave wid stages k-step (4c + wid) of each chunk: identity byte-mapping
  // wb[c*CHB + wid*STEPB + j*1024 + lane*16] -> lds[(c&1)*CHB + same offs]
  const char* gsrc0 = (const char*)wb + (size_t)wid * STEPB + (size_t)lane * 16;

  f32x4 acc[4];
#pragma unroll
  for (int nt = 0; nt < 4; ++nt) acc[nt] = 0.f;

  auto stage = [&](int c) {
    const char* s = gsrc0 + (size_t)c * CHB;
    char* d = (char*)lds + (size_t)((c & 1) * CHB) + (size_t)wid * STEPB;
#pragma unroll
    for (int j = 0; j < 12; ++j)
      __builtin_amdgcn_global_load_lds(
          (const __attribute__((address_space(1))) unsigned int*)(s + j * 1024),
          (__attribute__((address_space(3))) unsigned int*)(d + j * 1024),
          16, 0, 0);
  };

  // A loads for chunk c: k-range [128c, 128c+128); chunk 16 starts u exactly
  auto aload = [&](int c, f32x4* A) {
    const float* base = (c < 16) ? (hrow + c * 128) : (urow + (c - 16) * 128);
#pragma unroll
    for (int s = 0; s < CH; ++s) {
      A[2 * s] = *(const f32x4*)(base + s * 32);
      A[2 * s + 1] = *(const f32x4*)(base + s * 32 + 4);
    }
  };

  auto compute = [&](int bufsel, const f32x4* A) {
    const char* lb = (const char*)lds + bufsel * CHB + (size_t)lane * 16;
#pragma unroll
    for (int s = 0; s < CH; ++s) {
      const short8* ws = (const short8*)(lb + s * STEPB);
      short8 Bv[3][4];
#pragma unroll
      for (int p = 0; p < 3; ++p)
#pragma unroll
        for (int nt = 0; nt < 4; ++nt)
          Bv[p][nt] = ws[(p * 4 + nt) * 64];  // ds_read_b128, imm offsets

      const f32x4 c0 = A[2 * s], c1 = A[2 * s + 1];
      const float xs[8] = {c0[0], c0[1], c0[2], c0[3],
                           c1[0], c1[1], c1[2], c1[3]};
      u32x4 W0, W1, W2;
#pragma unroll
      for (int k2 = 0; k2 < 4; ++k2) {
        const float a = xs[2 * k2], bb = xs[2 * k2 + 1];
        const unsigned p0 = cvtpk(a, bb);
        const float a1 = a - __builtin_bit_cast(float, p0 << 16);
        const float b1 = bb - __builtin_bit_cast(float, p0 & 0xFFFF0000u);
        const unsigned p1 = cvtpk(a1, b1);
        const float a2 = a1 - __builtin_bit_cast(float, p1 << 16);
        const float b2 = b1 - __builtin_bit_cast(float, p1 & 0xFFFF0000u);
        const unsigned p2 = cvtpk(a2, b2);
        W0[k2] = p0; W1[k2] = p1; W2[k2] = p2;
      }
      const short8 A0 = __builtin_bit_cast(short8, W0);
      const short8 A1 = __builtin_bit_cast(short8, W1);
      const short8 A2 = __builtin_bit_cast(short8, W2);

#pragma unroll
      for (int nt = 0; nt < 4; ++nt) {
        acc[nt] = __builtin_amdgcn_mfma_f32_16x16x32_bf16(A0, Bv[0][nt], acc[nt], 0, 0, 0);
        acc[nt] = __builtin_amdgcn_mfma_f32_16x16x32_bf16(A0, Bv[1][nt], acc[nt], 0, 0, 0);
        acc[nt] = __builtin_amdgcn_mfma_f32_16x16x32_bf16(A1, Bv[0][nt], acc[nt], 0, 0, 0);
        acc[nt] = __builtin_amdgcn_mfma_f32_16x16x32_bf16(A1, Bv[1][nt], acc[nt], 0, 0, 0);
        acc[nt] = __builtin_amdgcn_mfma_f32_16x16x32_bf16(A0, Bv[2][nt], acc[nt], 0, 0, 0);
        acc[nt] = __builtin_amdgcn_mfma_f32_16x16x32_bf16(A2, Bv[0][nt], acc[nt], 0, 0, 0);
      }
    }
  };

  // prologue
  f32x4 Aa[8], Ab[8];
  stage(0);
  aload(0, Aa);
  __syncthreads();

  // paired double-buffer loop: static A-buffer selection (no runtime index)
#pragma unroll 1
  for (int cc = 0; cc < NCHUNK / 2; ++cc) {
    const int c0 = 2 * cc;
    aload(c0 + 1, Ab);
    stage(c0 + 1);
    compute(0, Aa);
    __syncthreads();          // vmcnt(0)+lgkm drain: buf1 staged, Ab ready
    if (c0 + 2 < NCHUNK) {
      aload(c0 + 2, Aa);
      stage(c0 + 2);
    }
    compute(1, Ab);
    __syncthreads();          // buf0 staged for next iter, Aa ready
  }

  // ---- epilogue: per-wave slab (aliases buf0 region; all compute done) ----
  float* slab = (float*)lds + (size_t)wid * (16 * LP);
  const int rowb = (lane >> 4) * 4;
#pragma unroll
  for (int nt = 0; nt < 4; ++nt)
#pragma unroll
    for (int r = 0; r < 4; ++r)
      slab[(rowb + r) * LP + nt * 16 + mm] = acc[nt][r];
  __syncthreads();

  const float bias = b[lane];
#pragma unroll 1
  for (int tt = 0; tt < 16; ++tt) {
    float g = slab[tt * LP + lane] + bias;

    float m = g;
#pragma unroll
    for (int off = 32; off > 0; off >>= 1)
      m = fmaxf(m, __shfl_xor(m, off));
    float pexp = __expf(g - m);
    float s = pexp;
#pragma unroll
    for (int off = 32; off > 0; off >>= 1)
      s += __shfl_xor(s, off);
    const float pn = pexp / s;

    float vv = pn;
    float topsum = 0.f;
    int sel = 0;
    for (int r = 0; r < TOPK; ++r) {
      float mv = vv;
      int mi = lane;
#pragma unroll
      for (int off = 32; off > 0; off >>= 1) {
        const float ov = __shfl_xor(mv, off);
        const int oi = __shfl_xor(mi, off);
        if (ov > mv || (ov == mv && oi < mi)) { mv = ov; mi = oi; }
      }
      topsum += mv;
      if (lane == mi) { sel = 1; vv = -1.f; }
    }

    out[(size_t)(tok0 + wid * 16 + tt) * NE + lane] =
        sel ? pn / (topsum + 1e-9f) : 0.f;
  }
}

extern "C" void kernel_launch(void* const* d_in, const int* in_sizes, int n_in,
                              void* d_out, int out_size, void* d_ws, size_t ws_size,
                              hipStream_t stream) {
  const float* h = (const float*)d_in[0];
  const float* u = (const float*)d_in[1];
  const float* W = (const float*)d_in[2];
  const float* b = (const float*)d_in[3];
  float* out = (float*)d_out;

  unsigned short* wb = (unsigned short*)d_ws;  // 72*6144 shorts = 884736 B

  const int n_tokens = in_sizes[0] / EMB;  // 16384

  hipLaunchKernelGGL(prep_w, dim3(KTOT * NE / 256), dim3(256), 0, stream, W, wb);
  hipLaunchKernelGGL(gate_mfma, dim3(n_tokens / 64), dim3(256), 0, stream,
                     h, u, wb, b, out);
}

// Round 4
// 253.678 us; speedup vs baseline: 1.1680x; 1.1680x over previous
//
#include <hip/hip_runtime.h>

#define EMB 2048
#define UDIM 256
#define KTOT 2304
#define NE 64
#define TOPK 8
#define TPB 16               // tokens per block: one 16-token MFMA tile
#define LP 65                // reduce-slab row stride (bank-conflict pad)
#define SSH 6144             // shorts per k-step in wb: 3 planes * 4 nt * 64 lanes * 8

typedef __attribute__((ext_vector_type(8))) short short8;
typedef __attribute__((ext_vector_type(4))) float f32x4;
typedef __attribute__((ext_vector_type(4))) unsigned int u32x4;

__device__ __forceinline__ unsigned short bf16h(float x) {
  unsigned uu = __builtin_bit_cast(unsigned, x);
  return (unsigned short)((uu + 0x7FFFu + ((uu >> 16) & 1u)) >> 16);
}
__device__ __forceinline__ float bf2f(unsigned short s) {
  return __builtin_bit_cast(float, ((unsigned)s) << 16);
}

// packed RNE f32x2 -> bf16x2
__device__ __forceinline__ unsigned cvtpk(float a, float b) {
  unsigned r;
  asm("v_cvt_pk_bf16_f32 %0, %1, %2" : "=v"(r) : "v"(a), "v"(b));
  return r;
}

// ---- prep: W fp32 [2304][64] -> triple-split bf16 in MFMA-FRAGMENT order ----
// wb[kstep][plane][nt][lane][j]:  lane = (kk>>3)*16 + (n&15), j = kk&7
// => each wave B-load is base + lane*16B: ONE coalesced dwordx4.
__global__ __launch_bounds__(256)
void prep_w(const float* __restrict__ W, unsigned short* __restrict__ wb) {
  const int flat = blockIdx.x * 256 + threadIdx.x;  // 0..147455
  const int k = flat >> 6;
  const int n = flat & 63;
  const float w = W[flat];
  const unsigned short h0 = bf16h(w);
  const float r1 = w - bf2f(h0);   // exact in fp32
  const unsigned short h1 = bf16h(r1);
  const float r2 = r1 - bf2f(h1);  // exact in fp32
  const unsigned short h2 = bf16h(r2);

  const int s = k >> 5;
  const int kk = k & 31;
  const int lane = (kk >> 3) * 16 + (n & 15);
  const int j = kk & 7;
  const int nt = n >> 4;
  const size_t base = (size_t)s * SSH + ((size_t)nt * 64 + lane) * 8 + j;
  wb[base] = h0;
  wb[base + 2048] = h1;
  wb[base + 4096] = h2;
}

// ---- main: triple-split bf16 MFMA GEMM, explicit B+A software pipeline ----
// 4 waves/block = 4-way K-split of one 16-token tile. MLP is the point:
// Bn[12] for step s+1 is loaded BEFORE the MFMAs consume Bc[12] of step s,
// forcing 14 loads in flight across the compute block (vmcnt(14) steady
// state, never a drain). 3 waves/SIMD via (256,3) covers the residue.
__global__ __launch_bounds__(256, 3)
void gate_mfma(const float* __restrict__ h, const float* __restrict__ u,
               const unsigned short* __restrict__ wb,
               const float* __restrict__ b, float* __restrict__ out) {
  __shared__ float slab[4][TPB * LP];  // 16.6 KB

  const int tid = threadIdx.x;
  const int lane = tid & 63;
  const int kq = __builtin_amdgcn_readfirstlane(tid >> 6);  // K slice 0..3
  const int mm = lane & 15;        // A: token-in-tile | B: expert-in-tile
  const int q8 = (lane >> 4) * 8;  // k-subgroup within frag
  const int tok0 = blockIdx.x * TPB;
  const int token = tok0 + mm;

  const float* hrow = h + (size_t)token * EMB + q8;
  const float* urow = u + (size_t)token * UDIM + q8;
  const unsigned short* wlane = wb + (size_t)lane * 8;  // per-lane frag base

  f32x4 acc[4];
#pragma unroll
  for (int nt = 0; nt < 4; ++nt) acc[nt] = 0.f;

  // convert one k-step of A (8 fp32) to triple-split bf16 and run 24 MFMAs
  auto body = [&](const f32x4& c0, const f32x4& c1, const short8* Bc) {
    const float xs[8] = {c0[0], c0[1], c0[2], c0[3],
                         c1[0], c1[1], c1[2], c1[3]};
    u32x4 W0, W1, W2;
#pragma unroll
    for (int k2 = 0; k2 < 4; ++k2) {
      const float a = xs[2 * k2], bb = xs[2 * k2 + 1];
      const unsigned p0 = cvtpk(a, bb);
      const float a1 = a - __builtin_bit_cast(float, p0 << 16);
      const float b1 = bb - __builtin_bit_cast(float, p0 & 0xFFFF0000u);
      const unsigned p1 = cvtpk(a1, b1);
      const float a2 = a1 - __builtin_bit_cast(float, p1 << 16);
      const float b2 = b1 - __builtin_bit_cast(float, p1 & 0xFFFF0000u);
      const unsigned p2 = cvtpk(a2, b2);
      W0[k2] = p0; W1[k2] = p1; W2[k2] = p2;
    }
    const short8 A0 = __builtin_bit_cast(short8, W0);
    const short8 A1 = __builtin_bit_cast(short8, W1);
    const short8 A2 = __builtin_bit_cast(short8, W2);

#pragma unroll
    for (int nt = 0; nt < 4; ++nt) {
      acc[nt] = __builtin_amdgcn_mfma_f32_16x16x32_bf16(A0, Bc[0 + nt], acc[nt], 0, 0, 0);
      acc[nt] = __builtin_amdgcn_mfma_f32_16x16x32_bf16(A0, Bc[4 + nt], acc[nt], 0, 0, 0);
      acc[nt] = __builtin_amdgcn_mfma_f32_16x16x32_bf16(A1, Bc[0 + nt], acc[nt], 0, 0, 0);
      acc[nt] = __builtin_amdgcn_mfma_f32_16x16x32_bf16(A1, Bc[4 + nt], acc[nt], 0, 0, 0);
      acc[nt] = __builtin_amdgcn_mfma_f32_16x16x32_bf16(A0, Bc[8 + nt], acc[nt], 0, 0, 0);
      acc[nt] = __builtin_amdgcn_mfma_f32_16x16x32_bf16(A2, Bc[0 + nt], acc[nt], 0, 0, 0);
    }
  };

  auto run = [&](const float* __restrict__ xp, int kw0, int nsteps) {
    const int as0 = kw0 >> 5;  // absolute k-step index
    // prologue: step-0 A and B in regs
    f32x4 c0 = *(const f32x4*)(xp);
    f32x4 c1 = *(const f32x4*)(xp + 4);
    short8 Bc[12];
    {
      const unsigned short* ws = wlane + (size_t)as0 * SSH;
#pragma unroll
      for (int q = 0; q < 12; ++q) Bc[q] = *(const short8*)(ws + q * 512);
    }
#pragma unroll 1
    for (int s = 0; s < nsteps - 1; ++s) {
      // issue next-step A (longest latency) then next-step B
      const f32x4 n0 = *(const f32x4*)(xp + (s + 1) * 32);
      const f32x4 n1 = *(const f32x4*)(xp + (s + 1) * 32 + 4);
      short8 Bn[12];
      const unsigned short* ws = wlane + (size_t)(as0 + s + 1) * SSH;
#pragma unroll
      for (int q = 0; q < 12; ++q) Bn[q] = *(const short8*)(ws + q * 512);

      body(c0, c1, Bc);  // consumes Bc while Bn/n0/n1 are in flight

      c0 = n0; c1 = n1;
#pragma unroll
      for (int q = 0; q < 12; ++q) Bc[q] = Bn[q];
    }
    body(c0, c1, Bc);  // final step, no prefetch
  };

  if (kq < 3) {
    run(hrow + kq * 576, kq * 576, 18);  // pure h: 576 k each
  } else {
    run(hrow + 1728, 1728, 10);          // h tail: [1728,2048)
    run(urow, 2048, 8);                  // u: [2048,2304)
  }

  // ---- K reduce: each wave writes its own slab buffer ----
  // D layout: row(token) = (lane>>4)*4 + reg, col(expert%16) = mm
  const int rowb = (lane >> 4) * 4;
#pragma unroll
  for (int nt = 0; nt < 4; ++nt)
#pragma unroll
    for (int r = 0; r < 4; ++r)
      slab[kq][(rowb + r) * LP + nt * 16 + mm] = acc[nt][r];
  __syncthreads();

  // ---- epilogue: wave kq handles tokens [4*kq, 4*kq+4); lane = expert ----
  const float bias = b[lane];
#pragma unroll
  for (int tt = 0; tt < 4; ++tt) {
    const int t = kq * 4 + tt;
    float g = slab[0][t * LP + lane] + slab[1][t * LP + lane] +
              slab[2][t * LP + lane] + slab[3][t * LP + lane] + bias;

    float m = g;
#pragma unroll
    for (int off = 32; off > 0; off >>= 1)
      m = fmaxf(m, __shfl_xor(m, off));
    float pexp = __expf(g - m);
    float s = pexp;
#pragma unroll
    for (int off = 32; off > 0; off >>= 1)
      s += __shfl_xor(s, off);
    const float pn = pexp / s;

    float vv = pn;
    float topsum = 0.f;
    int sel = 0;
    for (int r = 0; r < TOPK; ++r) {
      float mv = vv;
      int mi = lane;
#pragma unroll
      for (int off = 32; off > 0; off >>= 1) {
        const float ov = __shfl_xor(mv, off);
        const int oi = __shfl_xor(mi, off);
        if (ov > mv || (ov == mv && oi < mi)) { mv = ov; mi = oi; }
      }
      topsum += mv;
      if (lane == mi) { sel = 1; vv = -1.f; }
    }

    out[(size_t)(tok0 + t) * NE + lane] =
        sel ? pn / (topsum + 1e-9f) : 0.f;
  }
}

extern "C" void kernel_launch(void* const* d_in, const int* in_sizes, int n_in,
                              void* d_out, int out_size, void* d_ws, size_t ws_size,
                              hipStream_t stream) {
  const float* h = (const float*)d_in[0];
  const float* u = (const float*)d_in[1];
  const float* W = (const float*)d_in[2];
  const float* b = (const float*)d_in[3];
  float* out = (float*)d_out;

  unsigned short* wb = (unsigned short*)d_ws;  // 72*6144 shorts = 884736 B

  const int n_tokens = in_sizes[0] / EMB;  // 16384

  hipLaunchKernelGGL(prep_w, dim3(KTOT * NE / 256), dim3(256), 0, stream, W, wb);
  hipLaunchKernelGGL(gate_mfma, dim3(n_tokens / TPB), dim3(256), 0, stream,
                     h, u, wb, b, out);
}